// Round 15
// baseline (474.477 us; speedup 1.0000x reference)
//
#include <hip/hip_runtime.h>
#include <hip/hip_bf16.h>
#include <math.h>

#define NE 1024      // edges
#define NN 256       // nodes
#define NG 16        // graphs
#define EMB 64
#define KD 256       // MLP_DIM
#define BK 64        // gemm K-step
#define NUMEL_L0 20480
#define NUMEL_LN 69632
#define MSGW 704     // 192 + 64*3 + 64*5
#define MAXE 256

typedef __attribute__((ext_vector_type(8))) __bf16 bf16x8;
typedef __attribute__((ext_vector_type(4))) float f32x4;
typedef __attribute__((ext_vector_type(4))) unsigned int u32x4;

// ---------------- static device scratch ----------------
__device__ __align__(16) float g_sh[NE * 8];
__device__ __align__(16) float g_ef[NE * 8];
__device__ __align__(16) unsigned short g_hidb[3][NE * KD];              // bf16 hid per layer
__device__ __align__(16) unsigned short g_w2t0[(size_t)NUMEL_L0 * KD];   // 10.5 MB
__device__ __align__(16) unsigned short g_w2t1[(size_t)NUMEL_LN * KD];   // 35.7 MB
__device__ __align__(16) unsigned short g_w2t2[(size_t)NUMEL_LN * KD];   // 35.7 MB
__device__ __align__(16) unsigned short g_wb0[(size_t)NE * NUMEL_L0];    // 40 MB
__device__ __align__(16) unsigned short g_wb1[(size_t)NE * NUMEL_LN];    // 143 MB
__device__ __align__(16) unsigned short g_wb2[(size_t)NE * NUMEL_LN];    // 143 MB
__device__ __align__(16) float g_msgs[NE * MSGW];
__device__ __align__(16) float g_h0[NN * EMB];
__device__ __align__(16) float g_h1[NN * EMB * 3];
__device__ __align__(16) float g_h2[NN * EMB * 5];
__device__ int g_elist[NN * MAXE];
__device__ int g_ecnt[NN];
__device__ float g_cg[363];

__device__ __forceinline__ unsigned short f2b(float x) {
    __hip_bfloat16 h = __float2bfloat16(x);
    return *(unsigned short*)&h;
}
__device__ __forceinline__ float b2f(unsigned short u) {
    __hip_bfloat16 h;
    *(unsigned short*)&h = u;
    return __bfloat162float(h);
}

// async global->LDS 16B copy: per-lane global src, linear LDS dest (wave base + lane*16)
__device__ __forceinline__ void gld16(const void* g, void* l) {
    __builtin_amdgcn_global_load_lds(
        (const __attribute__((address_space(1))) unsigned int*)g,
        (__attribute__((address_space(3))) unsigned int*)l, 16, 0, 0);
}

// ---------------- path metadata ----------------
struct Path { int l1, l2, d1, d2, d3, mv, off, cgoff, tmpoff; };

// LN paths in reference order (grouped by l3: [0,3) l3=0, [3,7) l3=1, [7,11) l3=2)
__constant__ Path PLN[11] = {
    {0, 0, 1, 1, 1, 192, 0,     0,   0},
    {1, 1, 3, 3, 1, 192, 12288, 1,   64},
    {2, 2, 5, 5, 1, 192, 24576, 10,  128},
    {0, 1, 1, 3, 3, 64,  36864, 35,  192},
    {1, 0, 3, 1, 3, 64,  40960, 44,  384},
    {1, 2, 3, 5, 3, 64,  45056, 53,  576},
    {2, 1, 5, 3, 3, 64,  49152, 98,  768},
    {0, 2, 1, 5, 5, 64,  53248, 143, 960},
    {2, 0, 5, 1, 5, 64,  57344, 168, 1280},
    {1, 1, 3, 3, 5, 64,  61440, 193, 1600},
    {2, 2, 5, 5, 5, 64,  65536, 238, 1920},
};
__constant__ Path PL0[3] = {
    {0, 0, 1, 1, 1, 192, 0,     0,   0},
    {0, 1, 1, 3, 3, 64,  12288, 35,  64},
    {0, 2, 1, 5, 5, 64,  16384, 143, 256},
};

__device__ void init_cg_body() {
    for (int i = 0; i < 363; i++) g_cg[i] = 0.f;
    const float K3 = 0.57735026918962576f;   // 1/sqrt(3)
    const float K5 = 0.44721359549995794f;   // 1/sqrt(5)
    const float A  = 0.31622776601683794f;   // 1/sqrt(10)
    const float B  = 0.18257418583505536f;   // 1/sqrt(30)
    const float C2 = 0.36514837167011072f;   // 2/sqrt(30)
    const float P  = 0.23904572186687872f;   // sqrt(70)/35
    const float Q  = 0.20701966780270626f;   // sqrt(210)/70
    const float S  = 0.11952286093343936f;   // sqrt(70)/70
    g_cg[0] = 1.f;
    for (int i = 0; i < 3; i++) g_cg[1 + i * 3 + i] = K3;
    for (int i = 0; i < 5; i++) g_cg[10 + i * 5 + i] = K5;
    for (int i = 0; i < 3; i++) g_cg[35 + i * 3 + i] = K3;
    for (int i = 0; i < 3; i++) g_cg[44 + i * 3 + i] = K3;
    // (1,2,1) @53 : (3x5x3) flat i*15+j*3+k
    g_cg[53 + 1]  = A;  g_cg[53 + 15] = A;  g_cg[53 + 20] = A;
    g_cg[53 + 34] = A;  g_cg[53 + 11] = A;  g_cg[53 + 39] = A;
    g_cg[53 + 6]  = -B; g_cg[53 + 22] = -B; g_cg[53 + 38] = C2;
    g_cg[53 + 12] = A;  g_cg[53 + 28] = -A;
    // (2,1,1) @98 : (5x3x3) flat i*9+j*3+k
    g_cg[98 + 1]  = A;  g_cg[98 + 3]  = A;  g_cg[98 + 14] = A;
    g_cg[98 + 16] = A;  g_cg[98 + 29] = A;  g_cg[98 + 33] = A;
    g_cg[98 + 18] = -B; g_cg[98 + 22] = -B; g_cg[98 + 26] = C2;
    g_cg[98 + 36] = A;  g_cg[98 + 40] = -A;
    for (int i = 0; i < 5; i++) g_cg[143 + i * 5 + i] = K5;
    for (int i = 0; i < 5; i++) g_cg[168 + i * 5 + i] = K5;
    // (1,1,2) @193 : (3x3x5) flat i*15+j*5+k
    g_cg[193 + 5]  = A;  g_cg[193 + 15] = A;  g_cg[193 + 26] = A;
    g_cg[193 + 36] = A;  g_cg[193 + 13] = A;  g_cg[193 + 33] = A;
    g_cg[193 + 2]  = -B; g_cg[193 + 22] = -B; g_cg[193 + 42] = C2;
    g_cg[193 + 4]  = A;  g_cg[193 + 24] = -A;
    // (2,2,2) @238 : (5x5x5) flat i*25+j*5+k  (global sign flipped)
    g_cg[238 + 2]   = P;  g_cg[238 + 10]  = P;  g_cg[238 + 50]  = P;
    g_cg[238 + 8]   = -Q; g_cg[238 + 16]  = -Q; g_cg[238 + 28]  = -Q;
    g_cg[238 + 40]  = -Q; g_cg[238 + 76]  = -Q; g_cg[238 + 80]  = -Q;
    g_cg[238 + 32]  = -S; g_cg[238 + 36]  = -S; g_cg[238 + 56]  = -S;
    g_cg[238 + 34]  = Q;  g_cg[238 + 46]  = Q;  g_cg[238 + 106] = Q;
    g_cg[238 + 62]  = -P;
    g_cg[238 + 74]  = P;  g_cg[238 + 114] = P;  g_cg[238 + 122] = P;
    g_cg[238 + 68]  = -S; g_cg[238 + 88]  = -S; g_cg[238 + 92]  = -S;
    g_cg[238 + 94]  = -Q; g_cg[238 + 98]  = -Q; g_cg[238 + 118] = -Q;
}

// ---------------- fused setup: cg init / geometry / h init / edge lists ----------------
// blocks: 0 = cg, 1..4 = geom, 5..68 = inith, 69..324 = elist
__global__ __launch_bounds__(256) void k_setup(const int* ei, const float* pos,
                                               const int* atoms, const float* emb) {
    int bid = blockIdx.x, tid = threadIdx.x;
    if (bid == 0) {
        if (tid == 0) init_cg_body();
        return;
    }
    if (bid <= 4) {
        int e = (bid - 1) * 256 + tid;
        int recv = ei[e], send = ei[NE + e];
        float vx = pos[recv * 3 + 0] - pos[send * 3 + 0];
        float vy = pos[recv * 3 + 1] - pos[send * 3 + 1];
        float vz = pos[recv * 3 + 2] - pos[send * 3 + 2];
        float rn = sqrtf(vx * vx + vy * vy + vz * vz);
        float r = fmaxf(rn, 1e-6f);
        float x = vx / r, y = vy / r, z = vz / r;
        const float S3 = 1.7320508075688772f;
        const float S15 = 3.8729833462074170f;
        const float S5H = 1.1180339887498949f;
        const float S15H = 1.9364916731037085f;
        g_sh[e * 8 + 0] = S3 * x;
        g_sh[e * 8 + 1] = S3 * y;
        g_sh[e * 8 + 2] = S3 * z;
        g_sh[e * 8 + 3] = S15 * x * y;
        g_sh[e * 8 + 4] = S15 * y * z;
        g_sh[e * 8 + 5] = S5H * (3.f * z * z - 1.f);
        g_sh[e * 8 + 6] = S15 * x * z;
        g_sh[e * 8 + 7] = S15H * (x * x - y * y);
        float xr = r * 0.1f;
        float env = 0.f;
        if (xr < 1.f) {
            float x5 = xr * xr * xr * xr * xr;
            env = 1.f - 21.f * x5 + 35.f * x5 * xr - 15.f * x5 * xr * xr;
        }
        const float SB = 0.44721359549995794f;
        const float PI = 3.14159265358979323846f;
        for (int nb = 1; nb <= 8; nb++) {
            g_ef[e * 8 + nb - 1] = SB * sinf((float)nb * PI * r * 0.1f) / r * env;
        }
        return;
    }
    if (bid <= 68) {
        int idx = (bid - 5) * 256 + tid;  // over NN*EMB
        int n = idx / EMB, u = idx % EMB;
        g_h0[idx] = emb[atoms[n] * EMB + u];
        for (int k = 0; k < 3; k++) g_h1[idx * 3 + k] = 0.f;
        for (int k = 0; k < 5; k++) g_h2[idx * 5 + k] = 0.f;
        return;
    }
    {
        int n = bid - 69;
        int lane = tid & 63, w = tid >> 6;
        __shared__ int wsum[4];
        int mask = 0;
#pragma unroll
        for (int i = 0; i < 4; i++) {
            if (ei[tid * 4 + i] == n) mask |= 1 << i;
        }
        int nm = __popc(mask);
        int incl = nm;
#pragma unroll
        for (int off = 1; off < 64; off <<= 1) {
            int v = __shfl_up(incl, off);
            if (lane >= off) incl += v;
        }
        if (lane == 63) wsum[w] = incl;
        __syncthreads();
        int wbase = 0;
        for (int i = 0; i < w; i++) wbase += wsum[i];
        int base = wbase + incl - nm;
#pragma unroll
        for (int i = 0; i < 4; i++) {
            if (mask & (1 << i)) g_elist[n * MAXE + base++] = tid * 4 + i;
        }
        if (tid == 255) g_ecnt[n] = wbase + incl;
    }
}

// ---------------- ALL-LAYER W2 transpose+bf16 AND radial-MLP hid (one launch) -----------
// Weight pipeline is independent of the layer recurrence, so run all 3 layers upfront.
// blocks: [0,5120) L0 w2t; [5120,22528) L1 w2t; [22528,39936) L2 w2t; [39936,+3072) hid.
__global__ __launch_bounds__(256) void k_w2t_hid_all(
        const float* l0w2, const float* f2w,
        const float* l0w1, const float* l0b1, const float* f1w, const float* f1b) {
    __shared__ float t[32][33];
    int bid = blockIdx.x;
    if (bid < 39936) {
        int layer, lbid, numel;
        const float* w2;
        unsigned short* dst;
        if (bid < 5120)       { layer = 0; lbid = bid;          numel = NUMEL_L0; w2 = l0w2; dst = g_w2t0; }
        else if (bid < 22528) { layer = 1; lbid = bid - 5120;   numel = NUMEL_LN; w2 = f2w;  dst = g_w2t1; }
        else                  { layer = 2; lbid = bid - 22528;  numel = NUMEL_LN;
                                w2 = f2w + (size_t)KD * NUMEL_LN; dst = g_w2t2; }
        int n0 = (lbid >> 3) * 32, k0 = (lbid & 7) * 32;
        int tx = threadIdx.x & 31, ty = threadIdx.x >> 5;
#pragma unroll
        for (int i = 0; i < 4; i++) {
            int kl = ty * 4 + i;
            t[kl][tx] = w2[(size_t)(k0 + kl) * numel + n0 + tx];
        }
        __syncthreads();
#pragma unroll
        for (int i = 0; i < 4; i++) {
            int nl = ty * 4 + i;
            dst[(size_t)(n0 + nl) * KD + k0 + tx] = f2b(t[tx][nl]);
        }
    } else {
        int r = bid - 39936;           // 0..3071
        int layer = r >> 10, e = r & 1023;
        const float* w1 = layer == 0 ? l0w1 : f1w + (size_t)(layer - 1) * 8 * KD;
        const float* b1 = layer == 0 ? l0b1 : f1b + (size_t)(layer - 1) * KD;
        int m = threadIdx.x;
        float acc = b1[m];
        for (int nb = 0; nb < 8; nb++) acc += g_ef[e * 8 + nb] * w1[nb * KD + m];
        g_hidb[layer][e * KD + m] = f2b(fmaxf(acc, 0.f));
    }
}

// ---------------- ALL-LAYER bf16 MFMA GEMM (one launch) ----------------
// blocks: [0,4352) layer2; [4352,8704) layer1; [8704,9984) layer0 (LAST so wb0 is L3-hot
// for the immediately-following contract0). Per-layer XCD-aware decode as before.
__global__ __launch_bounds__(256) void k_gemm_all(const float* l0b2, const float* f2b_) {
    __shared__ unsigned short S[16384];
    int tid = threadIdx.x;
    int lane = tid & 63, wid = tid >> 6;
    int wm = wid >> 1, wn = wid & 1;
    int id = blockIdx.x;
    int layer, lid, numel;
    const unsigned short* hidb;
    const unsigned short* w2t;
    unsigned short* wb;
    const float* b2;
    if (id < 4352)      { layer = 2; lid = id;        numel = NUMEL_LN; hidb = g_hidb[2]; w2t = g_w2t2; wb = g_wb2; b2 = f2b_ + NUMEL_LN; }
    else if (id < 8704) { layer = 1; lid = id - 4352; numel = NUMEL_LN; hidb = g_hidb[1]; w2t = g_w2t1; wb = g_wb1; b2 = f2b_; }
    else                { layer = 0; lid = id - 8704; numel = NUMEL_L0; hidb = g_hidb[0]; w2t = g_w2t0; wb = g_wb0; b2 = l0b2; }
    int xcd = lid & 7;
    int q = lid >> 3;
    int mb = q & 7;
    int ytile = q >> 3;
    int nt = xcd + 8 * ytile;
    int m0 = mb * 128, n0 = nt * 128;
    int fr = lane & 15;
    int ko = (lane >> 4) * 8;

    const char* gA = (const char*)hidb;
    const char* gB = (const char*)w2t;
    f32x4 acc[4][4] = {};

    for (int kst = 0; kst < 4; kst++) {
#pragma unroll
        for (int i = 0; i < 4; i++) {   // A: 16KB
            int L = wid * 4096 + i * 1024 + lane * 16;
            int row = L >> 7, p = L & 127;
            int sp = p ^ ((row & 7) << 4);
            gld16(gA + ((size_t)(m0 + row) * KD + kst * BK) * 2 + sp, (char*)S + L);
        }
#pragma unroll
        for (int i = 0; i < 4; i++) {   // B: 16KB
            int L = wid * 4096 + i * 1024 + lane * 16;
            int row = L >> 7, p = L & 127;
            int sp = p ^ ((row & 7) << 4);
            gld16(gB + ((size_t)(n0 + row) * KD + kst * BK) * 2 + sp, (char*)S + 16384 + L);
        }
        __syncthreads();
#pragma unroll
        for (int ks = 0; ks < 2; ks++) {
            int klb = ks * 64 + ko * 2;
            bf16x8 af[4], bf_[4];
#pragma unroll
            for (int f = 0; f < 4; f++) {
                int ra = wm * 64 + f * 16 + fr;
                af[f] = *(bf16x8*)((char*)S + ra * 128 + (klb ^ ((ra & 7) << 4)));
                int rb = wn * 64 + f * 16 + fr;
                bf_[f] = *(bf16x8*)((char*)S + 16384 + rb * 128 + (klb ^ ((rb & 7) << 4)));
            }
#pragma unroll
            for (int i = 0; i < 4; i++)
#pragma unroll
                for (int j = 0; j < 4; j++)
                    acc[i][j] = __builtin_amdgcn_mfma_f32_16x16x32_bf16(af[i], bf_[j], acc[i][j], 0, 0, 0);
        }
        __syncthreads();
    }

    // epilogue: +bias -> bf16 -> LDS (swizzled) -> coalesced stores
#pragma unroll
    for (int j = 0; j < 4; j++) {
        int colL = wn * 64 + j * 16 + fr;
        float bb = b2[n0 + colL];
#pragma unroll
        for (int i = 0; i < 4; i++) {
#pragma unroll
            for (int r = 0; r < 4; r++) {
                int rowL = wm * 64 + i * 16 + (lane >> 4) * 4 + r;
                *(unsigned short*)((char*)S + rowL * 256 + ((colL * 2) ^ ((rowL & 7) << 4))) =
                    f2b(acc[i][j][r] + bb);
            }
        }
    }
    __syncthreads();
    for (int c = tid; c < 2048; c += 256) {
        int row = c >> 4, p16 = (c & 15) * 16;
        u32x4 v = *(u32x4*)((char*)S + row * 256 + (p16 ^ ((row & 7) << 4)));
        *(u32x4*)((char*)(wb + (size_t)(m0 + row) * numel + n0) + p16) = v;
    }
}

// ---------------- per-edge path contraction -> msgs (register streaming) ----------------
// Grid (NE, 3): block (e, grp) handles one l3-group of one edge. No w staging: w streamed
// straight to registers in the unrolled MAC loop; LDS = tmp only -> high occupancy.
__global__ __launch_bounds__(256) void k_contract(const int* ei, int layer) {
    int e = blockIdx.x;
    int grp = blockIdx.y;
    int tid = threadIdx.x;
    __shared__ float tmp[1280];
    int layer0 = (layer == 0) ? 1 : 0;
    int numel = layer0 ? NUMEL_L0 : NUMEL_LN;
    const unsigned short* wbase = layer == 0 ? g_wb0 : (layer == 1 ? g_wb1 : g_wb2);
    const Path* PT = layer0 ? PL0 : PLN;
    int npaths = layer0 ? 3 : 11;
    int pstart = layer0 ? grp : (grp == 0 ? 0 : (grp == 1 ? 3 : 7));
    int pend   = layer0 ? grp + 1 : (grp == 0 ? 3 : (grp == 1 ? 7 : 11));
    int tbase = PT[pstart].tmpoff;
    int tend  = (pend < npaths) ? PT[pend].tmpoff : (layer0 ? 576 : 2240);
    int ttot = tend - tbase;
    const unsigned short* wrow = wbase + (size_t)e * numel;
    int send = ei[NE + e];

    for (int t = tid; t < ttot; t += 256) {
        int tt = t + tbase;
        int p = pend - 1;
        while (tt < PT[p].tmpoff) p--;
        Path pp = PT[p];
        int rem = tt - pp.tmpoff;
        int u = rem / pp.d3, k = rem % pp.d3;
        float acc = 0.f;
        for (int i = 0; i < pp.d1; i++) {
            float hv = (pp.l1 == 0) ? g_h0[send * EMB + u]
                     : (pp.l1 == 1) ? g_h1[(send * EMB + u) * 3 + i]
                                    : g_h2[(send * EMB + u) * 5 + i];
            for (int j = 0; j < pp.d2; j++) {
                float sv = (pp.l2 == 0) ? 1.f
                         : (pp.l2 == 1 ? g_sh[e * 8 + j] : g_sh[e * 8 + 3 + j]);
                acc += hv * sv * g_cg[pp.cgoff + (i * pp.d2 + j) * pp.d3 + k];
            }
        }
        tmp[t] = acc;
    }
    __syncthreads();

    float alpha0 = layer0 ? 0.125f : 0.07216878364870323f;
    float alpha12 = layer0 ? 0.125f : 0.0625f;
    int v3 = tid / 3, k3 = tid - v3 * 3;
    int v5a = tid / 5, k5a = tid - v5a * 5;
    int p5b = 256 + tid;
    int v5b = p5b / 5, k5b = p5b - v5b * 5;
    float a0 = 0.f, a1 = 0.f;

    for (int p = pstart; p < pend; p++) {
        Path pp = PT[p];
        int to = pp.tmpoff - tbase;
        const unsigned short* wp = wrow + pp.off;
        if (pp.d3 == 1) {
            if (tid < 192) {
#pragma unroll 16
                for (int u = 0; u < 64; u++)
                    a0 += tmp[to + u] * b2f(wp[u * 192 + tid]);
            }
        } else if (pp.d3 == 3) {
            if (tid < 192) {
#pragma unroll 16
                for (int u = 0; u < 64; u++)
                    a0 += tmp[to + u * 3 + k3] * b2f(wp[u * 64 + v3]);
            }
        } else {
#pragma unroll 16
            for (int u = 0; u < 64; u++)
                a0 += tmp[to + u * 5 + k5a] * b2f(wp[u * 64 + v5a]);
            if (tid < 64) {
#pragma unroll 16
                for (int u = 0; u < 64; u++)
                    a1 += tmp[to + u * 5 + k5b] * b2f(wp[u * 64 + v5b]);
            }
        }
    }
    if (grp == 0) {
        if (tid < 192) g_msgs[e * MSGW + tid] = alpha0 * a0;
    } else if (grp == 1) {
        if (tid < 192) g_msgs[e * MSGW + 192 + tid] = alpha12 * a0;
    } else {
        g_msgs[e * MSGW + 384 + tid] = alpha12 * a0;
        if (tid < 64) g_msgs[e * MSGW + 640 + tid] = alpha12 * a1;
    }
}

// ---------------- per-node aggregate + gate + residual ----------------
__global__ __launch_bounds__(256) void k_agggate() {
    int n = blockIdx.x, tid = threadIdx.x;
    __shared__ float agg[MSGW];
    int cnt = g_ecnt[n];
    for (int d = tid; d < MSGW; d += 256) {
        float a = 0.f;
        for (int idx = 0; idx < cnt; idx++) {
            int e = g_elist[n * MAXE + idx];
            a += g_msgs[e * MSGW + d];
        }
        agg[d] = a;
    }
    __syncthreads();
    if (tid < EMB) {
        int u = tid;
        float s0 = agg[u], s1 = agg[64 + u], s2 = agg[128 + u];
        float sg0 = 1.f / (1.f + expf(-s0));
        float g0 = s0 * sg0;
        float sg1 = 1.f / (1.f + expf(-s1));
        float sg2 = 1.f / (1.f + expf(-s2));
        g_h0[n * EMB + u] += g0;
        for (int k = 0; k < 3; k++) g_h1[(n * EMB + u) * 3 + k] += agg[192 + u * 3 + k] * sg1;
        for (int k = 0; k < 5; k++) g_h2[(n * EMB + u) * 5 + k] += agg[384 + u * 5 + k] * sg2;
    }
}

// ---------------- fused pooling + prediction head (1 block, 16 waves = 16 graphs) --------
__global__ __launch_bounds__(1024) void k_poolhead(const int* batch, const float* w1,
                                                   const float* b1, const float* w2,
                                                   const float* b2, float* out) {
    __shared__ float pl[NG * EMB];
    int g = threadIdx.x >> 6, u = threadIdx.x & 63;
    float a = 0.f;
    for (int n = 0; n < NN; n++)
        if (batch[n] == g) a += g_h0[n * EMB + u];
    pl[g * EMB + u] = a;
    __syncthreads();
    float t = b1[u];
    for (int uu = 0; uu < EMB; uu++) t += pl[g * EMB + uu] * w1[uu * EMB + u];
    t = fmaxf(t, 0.f);
    float contrib = t * w2[u];
    for (int off = 32; off > 0; off >>= 1) contrib += __shfl_down(contrib, off);
    if (u == 0) out[g] = contrib + b2[0];
}

extern "C" void kernel_launch(void* const* d_in, const int* in_sizes, int n_in,
                              void* d_out, int out_size, void* d_ws, size_t ws_size,
                              hipStream_t stream) {
    const int* atoms = (const int*)d_in[0];
    const float* pos = (const float*)d_in[1];
    const int* ei = (const int*)d_in[2];
    const int* batch = (const int*)d_in[3];
    const float* emb = (const float*)d_in[4];
    const float* l0w1 = (const float*)d_in[5];
    const float* l0b1 = (const float*)d_in[6];
    const float* l0w2 = (const float*)d_in[7];
    const float* l0b2 = (const float*)d_in[8];
    const float* f1w = (const float*)d_in[9];
    const float* f1b = (const float*)d_in[10];
    const float* f2w = (const float*)d_in[11];
    const float* f2b_ = (const float*)d_in[12];
    const float* pw1 = (const float*)d_in[13];
    const float* pb1 = (const float*)d_in[14];
    const float* pw2 = (const float*)d_in[15];
    const float* pb2 = (const float*)d_in[16];
    float* out = (float*)d_out;

    k_setup<<<dim3(325), dim3(256), 0, stream>>>(ei, pos, atoms, emb);
    k_w2t_hid_all<<<dim3(43008), dim3(256), 0, stream>>>(l0w2, f2w, l0w1, l0b1, f1w, f1b);
    k_gemm_all<<<dim3(9984), dim3(256), 0, stream>>>(l0b2, f2b_);

    for (int layer = 0; layer < 3; layer++) {
        k_contract<<<dim3(NE, 3), dim3(256), 0, stream>>>(ei, layer);
        k_agggate<<<dim3(NN), dim3(256), 0, stream>>>();
    }

    k_poolhead<<<dim3(1), dim3(1024), 0, stream>>>(batch, pw1, pb1, pw2, pb2, out);
}

// Round 16
// 419.707 us; speedup vs baseline: 1.1305x; 1.1305x over previous
//
#include <hip/hip_runtime.h>
#include <hip/hip_bf16.h>
#include <math.h>

#define NE 1024      // edges
#define NN 256       // nodes
#define NG 16        // graphs
#define EMB 64
#define KD 256       // MLP_DIM
#define BK 64        // gemm K-step
#define NUMEL_L0 20480
#define NUMEL_LN 69632
#define MSGW 704     // 192 + 64*3 + 64*5
#define MAXE 256

typedef __attribute__((ext_vector_type(8))) __bf16 bf16x8;
typedef __attribute__((ext_vector_type(4))) float f32x4;
typedef __attribute__((ext_vector_type(4))) unsigned int u32x4;

// ---------------- static device scratch ----------------
__device__ __align__(16) float g_sh[NE * 8];
__device__ __align__(16) float g_ef[NE * 8];
__device__ __align__(16) unsigned short g_hidb[3][NE * KD];              // bf16 hid per layer
__device__ __align__(16) unsigned short g_w2t0[(size_t)NUMEL_L0 * KD];   // 10.5 MB
__device__ __align__(16) unsigned short g_w2t1[(size_t)NUMEL_LN * KD];   // 35.7 MB
__device__ __align__(16) unsigned short g_w2t2[(size_t)NUMEL_LN * KD];   // 35.7 MB
__device__ __align__(16) unsigned short g_wb[(size_t)NE * NUMEL_LN];     // 143 MB, reused per layer
__device__ __align__(16) float g_msgs[NE * MSGW];
__device__ __align__(16) float g_h0[NN * EMB];
__device__ __align__(16) float g_h1[NN * EMB * 3];
__device__ __align__(16) float g_h2[NN * EMB * 5];
__device__ int g_elist[NN * MAXE];
__device__ int g_ecnt[NN];
__device__ float g_cg[363];

__device__ __forceinline__ unsigned short f2b(float x) {
    __hip_bfloat16 h = __float2bfloat16(x);
    return *(unsigned short*)&h;
}
__device__ __forceinline__ float b2f(unsigned short u) {
    __hip_bfloat16 h;
    *(unsigned short*)&h = u;
    return __bfloat162float(h);
}

// async global->LDS 16B copy: per-lane global src, linear LDS dest (wave base + lane*16)
__device__ __forceinline__ void gld16(const void* g, void* l) {
    __builtin_amdgcn_global_load_lds(
        (const __attribute__((address_space(1))) unsigned int*)g,
        (__attribute__((address_space(3))) unsigned int*)l, 16, 0, 0);
}

// ---------------- path metadata ----------------
struct Path { int l1, l2, d1, d2, d3, mv, off, cgoff, tmpoff; };

// LN paths in reference order (grouped by l3: [0,3) l3=0, [3,7) l3=1, [7,11) l3=2)
__constant__ Path PLN[11] = {
    {0, 0, 1, 1, 1, 192, 0,     0,   0},
    {1, 1, 3, 3, 1, 192, 12288, 1,   64},
    {2, 2, 5, 5, 1, 192, 24576, 10,  128},
    {0, 1, 1, 3, 3, 64,  36864, 35,  192},
    {1, 0, 3, 1, 3, 64,  40960, 44,  384},
    {1, 2, 3, 5, 3, 64,  45056, 53,  576},
    {2, 1, 5, 3, 3, 64,  49152, 98,  768},
    {0, 2, 1, 5, 5, 64,  53248, 143, 960},
    {2, 0, 5, 1, 5, 64,  57344, 168, 1280},
    {1, 1, 3, 3, 5, 64,  61440, 193, 1600},
    {2, 2, 5, 5, 5, 64,  65536, 238, 1920},
};
__constant__ Path PL0[3] = {
    {0, 0, 1, 1, 1, 192, 0,     0,   0},
    {0, 1, 1, 3, 3, 64,  12288, 35,  64},
    {0, 2, 1, 5, 5, 64,  16384, 143, 256},
};

__device__ void init_cg_body() {
    for (int i = 0; i < 363; i++) g_cg[i] = 0.f;
    const float K3 = 0.57735026918962576f;   // 1/sqrt(3)
    const float K5 = 0.44721359549995794f;   // 1/sqrt(5)
    const float A  = 0.31622776601683794f;   // 1/sqrt(10)
    const float B  = 0.18257418583505536f;   // 1/sqrt(30)
    const float C2 = 0.36514837167011072f;   // 2/sqrt(30)
    const float P  = 0.23904572186687872f;   // sqrt(70)/35
    const float Q  = 0.20701966780270626f;   // sqrt(210)/70
    const float S  = 0.11952286093343936f;   // sqrt(70)/70
    g_cg[0] = 1.f;
    for (int i = 0; i < 3; i++) g_cg[1 + i * 3 + i] = K3;
    for (int i = 0; i < 5; i++) g_cg[10 + i * 5 + i] = K5;
    for (int i = 0; i < 3; i++) g_cg[35 + i * 3 + i] = K3;
    for (int i = 0; i < 3; i++) g_cg[44 + i * 3 + i] = K3;
    // (1,2,1) @53 : (3x5x3) flat i*15+j*3+k
    g_cg[53 + 1]  = A;  g_cg[53 + 15] = A;  g_cg[53 + 20] = A;
    g_cg[53 + 34] = A;  g_cg[53 + 11] = A;  g_cg[53 + 39] = A;
    g_cg[53 + 6]  = -B; g_cg[53 + 22] = -B; g_cg[53 + 38] = C2;
    g_cg[53 + 12] = A;  g_cg[53 + 28] = -A;
    // (2,1,1) @98 : (5x3x3) flat i*9+j*3+k
    g_cg[98 + 1]  = A;  g_cg[98 + 3]  = A;  g_cg[98 + 14] = A;
    g_cg[98 + 16] = A;  g_cg[98 + 29] = A;  g_cg[98 + 33] = A;
    g_cg[98 + 18] = -B; g_cg[98 + 22] = -B; g_cg[98 + 26] = C2;
    g_cg[98 + 36] = A;  g_cg[98 + 40] = -A;
    for (int i = 0; i < 5; i++) g_cg[143 + i * 5 + i] = K5;
    for (int i = 0; i < 5; i++) g_cg[168 + i * 5 + i] = K5;
    // (1,1,2) @193 : (3x3x5) flat i*15+j*5+k
    g_cg[193 + 5]  = A;  g_cg[193 + 15] = A;  g_cg[193 + 26] = A;
    g_cg[193 + 36] = A;  g_cg[193 + 13] = A;  g_cg[193 + 33] = A;
    g_cg[193 + 2]  = -B; g_cg[193 + 22] = -B; g_cg[193 + 42] = C2;
    g_cg[193 + 4]  = A;  g_cg[193 + 24] = -A;
    // (2,2,2) @238 : (5x5x5) flat i*25+j*5+k  (global sign flipped)
    g_cg[238 + 2]   = P;  g_cg[238 + 10]  = P;  g_cg[238 + 50]  = P;
    g_cg[238 + 8]   = -Q; g_cg[238 + 16]  = -Q; g_cg[238 + 28]  = -Q;
    g_cg[238 + 40]  = -Q; g_cg[238 + 76]  = -Q; g_cg[238 + 80]  = -Q;
    g_cg[238 + 32]  = -S; g_cg[238 + 36]  = -S; g_cg[238 + 56]  = -S;
    g_cg[238 + 34]  = Q;  g_cg[238 + 46]  = Q;  g_cg[238 + 106] = Q;
    g_cg[238 + 62]  = -P;
    g_cg[238 + 74]  = P;  g_cg[238 + 114] = P;  g_cg[238 + 122] = P;
    g_cg[238 + 68]  = -S; g_cg[238 + 88]  = -S; g_cg[238 + 92]  = -S;
    g_cg[238 + 94]  = -Q; g_cg[238 + 98]  = -Q; g_cg[238 + 118] = -Q;
}

// ---------------- fused setup: cg / geom / inith / elist / ALL-layer w2t ----------------
// blocks: 0 = cg, 1..4 = geom, 5..68 = inith, 69..324 = elist, 325..40260 = w2t (3 layers)
__global__ __launch_bounds__(256) void k_setup(const int* ei, const float* pos,
                                               const int* atoms, const float* emb,
                                               const float* l0w2, const float* f2w) {
    int bid = blockIdx.x, tid = threadIdx.x;
    if (bid == 0) {
        if (tid == 0) init_cg_body();
        return;
    }
    if (bid <= 4) {
        int e = (bid - 1) * 256 + tid;
        int recv = ei[e], send = ei[NE + e];
        float vx = pos[recv * 3 + 0] - pos[send * 3 + 0];
        float vy = pos[recv * 3 + 1] - pos[send * 3 + 1];
        float vz = pos[recv * 3 + 2] - pos[send * 3 + 2];
        float rn = sqrtf(vx * vx + vy * vy + vz * vz);
        float r = fmaxf(rn, 1e-6f);
        float x = vx / r, y = vy / r, z = vz / r;
        const float S3 = 1.7320508075688772f;
        const float S15 = 3.8729833462074170f;
        const float S5H = 1.1180339887498949f;
        const float S15H = 1.9364916731037085f;
        g_sh[e * 8 + 0] = S3 * x;
        g_sh[e * 8 + 1] = S3 * y;
        g_sh[e * 8 + 2] = S3 * z;
        g_sh[e * 8 + 3] = S15 * x * y;
        g_sh[e * 8 + 4] = S15 * y * z;
        g_sh[e * 8 + 5] = S5H * (3.f * z * z - 1.f);
        g_sh[e * 8 + 6] = S15 * x * z;
        g_sh[e * 8 + 7] = S15H * (x * x - y * y);
        float xr = r * 0.1f;
        float env = 0.f;
        if (xr < 1.f) {
            float x5 = xr * xr * xr * xr * xr;
            env = 1.f - 21.f * x5 + 35.f * x5 * xr - 15.f * x5 * xr * xr;
        }
        const float SB = 0.44721359549995794f;
        const float PI = 3.14159265358979323846f;
        for (int nb = 1; nb <= 8; nb++) {
            g_ef[e * 8 + nb - 1] = SB * sinf((float)nb * PI * r * 0.1f) / r * env;
        }
        return;
    }
    if (bid <= 68) {
        int idx = (bid - 5) * 256 + tid;  // over NN*EMB
        int n = idx / EMB, u = idx % EMB;
        g_h0[idx] = emb[atoms[n] * EMB + u];
        for (int k = 0; k < 3; k++) g_h1[idx * 3 + k] = 0.f;
        for (int k = 0; k < 5; k++) g_h2[idx * 5 + k] = 0.f;
        return;
    }
    if (bid <= 324) {
        int n = bid - 69;
        int lane = tid & 63, w = tid >> 6;
        __shared__ int wsum[4];
        int mask = 0;
#pragma unroll
        for (int i = 0; i < 4; i++) {
            if (ei[tid * 4 + i] == n) mask |= 1 << i;
        }
        int nm = __popc(mask);
        int incl = nm;
#pragma unroll
        for (int off = 1; off < 64; off <<= 1) {
            int v = __shfl_up(incl, off);
            if (lane >= off) incl += v;
        }
        if (lane == 63) wsum[w] = incl;
        __syncthreads();
        int wbase = 0;
        for (int i = 0; i < w; i++) wbase += wsum[i];
        int base = wbase + incl - nm;
#pragma unroll
        for (int i = 0; i < 4; i++) {
            if (mask & (1 << i)) g_elist[n * MAXE + base++] = tid * 4 + i;
        }
        if (tid == 255) g_ecnt[n] = wbase + incl;
        return;
    }
    // w2t: blocks 325..40260 — reads only inputs, independent of all other setup work
    {
        __shared__ float t[32][33];
        int wbid = bid - 325;
        int lbid, numel;
        const float* w2;
        unsigned short* dst;
        if (wbid < 5120)       { lbid = wbid;         numel = NUMEL_L0; w2 = l0w2; dst = g_w2t0; }
        else if (wbid < 22528) { lbid = wbid - 5120;  numel = NUMEL_LN; w2 = f2w;  dst = g_w2t1; }
        else                   { lbid = wbid - 22528; numel = NUMEL_LN;
                                 w2 = f2w + (size_t)KD * NUMEL_LN; dst = g_w2t2; }
        int n0 = (lbid >> 3) * 32, k0 = (lbid & 7) * 32;
        int tx = tid & 31, ty = tid >> 5;
#pragma unroll
        for (int i = 0; i < 4; i++) {
            int kl = ty * 4 + i;
            t[kl][tx] = w2[(size_t)(k0 + kl) * numel + n0 + tx];
        }
        __syncthreads();
#pragma unroll
        for (int i = 0; i < 4; i++) {
            int nl = ty * 4 + i;
            dst[(size_t)(n0 + nl) * KD + k0 + tx] = f2b(t[tx][nl]);
        }
    }
}

// ---------------- ALL-layer radial MLP hid (one launch, needs g_ef) ----------------
__global__ __launch_bounds__(256) void k_hid_all(const float* l0w1, const float* l0b1,
                                                 const float* f1w, const float* f1b) {
    int r = blockIdx.x;                   // 0..3071
    int layer = r >> 10, e = r & 1023;
    const float* w1 = layer == 0 ? l0w1 : f1w + (size_t)(layer - 1) * 8 * KD;
    const float* b1 = layer == 0 ? l0b1 : f1b + (size_t)(layer - 1) * KD;
    int m = threadIdx.x;
    float acc = b1[m];
    for (int nb = 0; nb < 8; nb++) acc += g_ef[e * 8 + nb] * w1[nb * KD + m];
    g_hidb[layer][e * KD + m] = f2b(fmaxf(acc, 0.f));
}

// ---------------- per-layer bf16 MFMA GEMM: g_wb = hidb[L] @ W2[L] + b2 ----------------
// 1D grid, decoded so the 8 M-blocks of one N-tile are dispatch-adjacent on one XCD.
// A/B staged via global_load_lds (linear LDS dest + inverse-swizzled global source).
__global__ __launch_bounds__(256) void k_gemm_mfma(const float* b2, int numel, int layer) {
    __shared__ unsigned short S[16384];  // 32 KB
    int tid = threadIdx.x;
    int lane = tid & 63, wid = tid >> 6;
    int wm = wid >> 1, wn = wid & 1;
    int id = blockIdx.x;
    int xcd = id & 7;
    int q = id >> 3;
    int mb = q & 7;
    int ytile = q >> 3;
    int nt = xcd + 8 * ytile;
    int m0 = mb * 128, n0 = nt * 128;
    int fr = lane & 15;
    int ko = (lane >> 4) * 8;

    const unsigned short* w2t = layer == 0 ? g_w2t0 : (layer == 1 ? g_w2t1 : g_w2t2);
    const char* gA = (const char*)g_hidb[layer];
    const char* gB = (const char*)w2t;
    f32x4 acc[4][4] = {};

    for (int kst = 0; kst < 4; kst++) {
#pragma unroll
        for (int i = 0; i < 4; i++) {   // A: 16KB
            int L = wid * 4096 + i * 1024 + lane * 16;
            int row = L >> 7, p = L & 127;
            int sp = p ^ ((row & 7) << 4);
            gld16(gA + ((size_t)(m0 + row) * KD + kst * BK) * 2 + sp, (char*)S + L);
        }
#pragma unroll
        for (int i = 0; i < 4; i++) {   // B: 16KB
            int L = wid * 4096 + i * 1024 + lane * 16;
            int row = L >> 7, p = L & 127;
            int sp = p ^ ((row & 7) << 4);
            gld16(gB + ((size_t)(n0 + row) * KD + kst * BK) * 2 + sp, (char*)S + 16384 + L);
        }
        __syncthreads();
#pragma unroll
        for (int ks = 0; ks < 2; ks++) {
            int klb = ks * 64 + ko * 2;
            bf16x8 af[4], bf_[4];
#pragma unroll
            for (int f = 0; f < 4; f++) {
                int ra = wm * 64 + f * 16 + fr;
                af[f] = *(bf16x8*)((char*)S + ra * 128 + (klb ^ ((ra & 7) << 4)));
                int rb = wn * 64 + f * 16 + fr;
                bf_[f] = *(bf16x8*)((char*)S + 16384 + rb * 128 + (klb ^ ((rb & 7) << 4)));
            }
#pragma unroll
            for (int i = 0; i < 4; i++)
#pragma unroll
                for (int j = 0; j < 4; j++)
                    acc[i][j] = __builtin_amdgcn_mfma_f32_16x16x32_bf16(af[i], bf_[j], acc[i][j], 0, 0, 0);
        }
        __syncthreads();
    }

    // epilogue: +bias -> bf16 -> LDS (swizzled) -> coalesced stores
#pragma unroll
    for (int j = 0; j < 4; j++) {
        int colL = wn * 64 + j * 16 + fr;
        float bb = b2[n0 + colL];
#pragma unroll
        for (int i = 0; i < 4; i++) {
#pragma unroll
            for (int r = 0; r < 4; r++) {
                int rowL = wm * 64 + i * 16 + (lane >> 4) * 4 + r;
                *(unsigned short*)((char*)S + rowL * 256 + ((colL * 2) ^ ((rowL & 7) << 4))) =
                    f2b(acc[i][j][r] + bb);
            }
        }
    }
    __syncthreads();
    for (int c = tid; c < 2048; c += 256) {
        int row = c >> 4, p16 = (c & 15) * 16;
        u32x4 v = *(u32x4*)((char*)S + row * 256 + (p16 ^ ((row & 7) << 4)));
        *(u32x4*)((char*)(g_wb + (size_t)(m0 + row) * numel + n0) + p16) = v;
    }
}

// ---------------- per-edge path contraction -> msgs (register streaming) ----------------
// Grid (NE, 3): block (e, grp) handles one l3-group of one edge. w streamed straight to
// registers in the unrolled MAC loop (g_wb L3-hot from the just-finished gemm).
__global__ __launch_bounds__(256) void k_contract(const int* ei, int layer) {
    int e = blockIdx.x;
    int grp = blockIdx.y;
    int tid = threadIdx.x;
    __shared__ float tmp[1280];
    int layer0 = (layer == 0) ? 1 : 0;
    int numel = layer0 ? NUMEL_L0 : NUMEL_LN;
    const Path* PT = layer0 ? PL0 : PLN;
    int npaths = layer0 ? 3 : 11;
    int pstart = layer0 ? grp : (grp == 0 ? 0 : (grp == 1 ? 3 : 7));
    int pend   = layer0 ? grp + 1 : (grp == 0 ? 3 : (grp == 1 ? 7 : 11));
    int tbase = PT[pstart].tmpoff;
    int tend  = (pend < npaths) ? PT[pend].tmpoff : (layer0 ? 576 : 2240);
    int ttot = tend - tbase;
    const unsigned short* wrow = g_wb + (size_t)e * numel;
    int send = ei[NE + e];

    for (int t = tid; t < ttot; t += 256) {
        int tt = t + tbase;
        int p = pend - 1;
        while (tt < PT[p].tmpoff) p--;
        Path pp = PT[p];
        int rem = tt - pp.tmpoff;
        int u = rem / pp.d3, k = rem % pp.d3;
        float acc = 0.f;
        for (int i = 0; i < pp.d1; i++) {
            float hv = (pp.l1 == 0) ? g_h0[send * EMB + u]
                     : (pp.l1 == 1) ? g_h1[(send * EMB + u) * 3 + i]
                                    : g_h2[(send * EMB + u) * 5 + i];
            for (int j = 0; j < pp.d2; j++) {
                float sv = (pp.l2 == 0) ? 1.f
                         : (pp.l2 == 1 ? g_sh[e * 8 + j] : g_sh[e * 8 + 3 + j]);
                acc += hv * sv * g_cg[pp.cgoff + (i * pp.d2 + j) * pp.d3 + k];
            }
        }
        tmp[t] = acc;
    }
    __syncthreads();

    float alpha0 = layer0 ? 0.125f : 0.07216878364870323f;
    float alpha12 = layer0 ? 0.125f : 0.0625f;
    int v3 = tid / 3, k3 = tid - v3 * 3;
    int v5a = tid / 5, k5a = tid - v5a * 5;
    int p5b = 256 + tid;
    int v5b = p5b / 5, k5b = p5b - v5b * 5;
    float a0 = 0.f, a1 = 0.f;

    for (int p = pstart; p < pend; p++) {
        Path pp = PT[p];
        int to = pp.tmpoff - tbase;
        const unsigned short* wp = wrow + pp.off;
        if (pp.d3 == 1) {
            if (tid < 192) {
#pragma unroll 16
                for (int u = 0; u < 64; u++)
                    a0 += tmp[to + u] * b2f(wp[u * 192 + tid]);
            }
        } else if (pp.d3 == 3) {
            if (tid < 192) {
#pragma unroll 16
                for (int u = 0; u < 64; u++)
                    a0 += tmp[to + u * 3 + k3] * b2f(wp[u * 64 + v3]);
            }
        } else {
#pragma unroll 16
            for (int u = 0; u < 64; u++)
                a0 += tmp[to + u * 5 + k5a] * b2f(wp[u * 64 + v5a]);
            if (tid < 64) {
#pragma unroll 16
                for (int u = 0; u < 64; u++)
                    a1 += tmp[to + u * 5 + k5b] * b2f(wp[u * 64 + v5b]);
            }
        }
    }
    if (grp == 0) {
        if (tid < 192) g_msgs[e * MSGW + tid] = alpha0 * a0;
    } else if (grp == 1) {
        if (tid < 192) g_msgs[e * MSGW + 192 + tid] = alpha12 * a0;
    } else {
        g_msgs[e * MSGW + 384 + tid] = alpha12 * a0;
        if (tid < 64) g_msgs[e * MSGW + 640 + tid] = alpha12 * a1;
    }
}

// ---------------- per-node aggregate + gate + residual ----------------
__global__ __launch_bounds__(256) void k_agggate() {
    int n = blockIdx.x, tid = threadIdx.x;
    __shared__ float agg[MSGW];
    int cnt = g_ecnt[n];
    for (int d = tid; d < MSGW; d += 256) {
        float a = 0.f;
        for (int idx = 0; idx < cnt; idx++) {
            int e = g_elist[n * MAXE + idx];
            a += g_msgs[e * MSGW + d];
        }
        agg[d] = a;
    }
    __syncthreads();
    if (tid < EMB) {
        int u = tid;
        float s0 = agg[u], s1 = agg[64 + u], s2 = agg[128 + u];
        float sg0 = 1.f / (1.f + expf(-s0));
        float g0 = s0 * sg0;
        float sg1 = 1.f / (1.f + expf(-s1));
        float sg2 = 1.f / (1.f + expf(-s2));
        g_h0[n * EMB + u] += g0;
        for (int k = 0; k < 3; k++) g_h1[(n * EMB + u) * 3 + k] += agg[192 + u * 3 + k] * sg1;
        for (int k = 0; k < 5; k++) g_h2[(n * EMB + u) * 5 + k] += agg[384 + u * 5 + k] * sg2;
    }
}

// ---------------- fused pooling + prediction head (1 block, 16 waves = 16 graphs) --------
__global__ __launch_bounds__(1024) void k_poolhead(const int* batch, const float* w1,
                                                   const float* b1, const float* w2,
                                                   const float* b2, float* out) {
    __shared__ float pl[NG * EMB];
    int g = threadIdx.x >> 6, u = threadIdx.x & 63;
    float a = 0.f;
    for (int n = 0; n < NN; n++)
        if (batch[n] == g) a += g_h0[n * EMB + u];
    pl[g * EMB + u] = a;
    __syncthreads();
    float t = b1[u];
    for (int uu = 0; uu < EMB; uu++) t += pl[g * EMB + uu] * w1[uu * EMB + u];
    t = fmaxf(t, 0.f);
    float contrib = t * w2[u];
    for (int off = 32; off > 0; off >>= 1) contrib += __shfl_down(contrib, off);
    if (u == 0) out[g] = contrib + b2[0];
}

extern "C" void kernel_launch(void* const* d_in, const int* in_sizes, int n_in,
                              void* d_out, int out_size, void* d_ws, size_t ws_size,
                              hipStream_t stream) {
    const int* atoms = (const int*)d_in[0];
    const float* pos = (const float*)d_in[1];
    const int* ei = (const int*)d_in[2];
    const int* batch = (const int*)d_in[3];
    const float* emb = (const float*)d_in[4];
    const float* l0w1 = (const float*)d_in[5];
    const float* l0b1 = (const float*)d_in[6];
    const float* l0w2 = (const float*)d_in[7];
    const float* l0b2 = (const float*)d_in[8];
    const float* f1w = (const float*)d_in[9];
    const float* f1b = (const float*)d_in[10];
    const float* f2w = (const float*)d_in[11];
    const float* f2b_ = (const float*)d_in[12];
    const float* pw1 = (const float*)d_in[13];
    const float* pb1 = (const float*)d_in[14];
    const float* pw2 = (const float*)d_in[15];
    const float* pb2 = (const float*)d_in[16];
    float* out = (float*)d_out;

    k_setup<<<dim3(40261), dim3(256), 0, stream>>>(ei, pos, atoms, emb, l0w2, f2w);
    k_hid_all<<<dim3(3072), dim3(256), 0, stream>>>(l0w1, l0b1, f1w, f1b);

    for (int layer = 0; layer < 3; layer++) {
        const float* b2 = layer == 0 ? l0b2 : f2b_ + (size_t)(layer - 1) * NUMEL_LN;
        int numel = layer == 0 ? NUMEL_L0 : NUMEL_LN;
        k_gemm_mfma<<<dim3((numel / 128) * (NE / 128)), dim3(256), 0, stream>>>(b2, numel, layer);
        k_contract<<<dim3(NE, 3), dim3(256), 0, stream>>>(ei, layer);
        k_agggate<<<dim3(NN), dim3(256), 0, stream>>>();
    }

    k_poolhead<<<dim3(1), dim3(1024), 0, stream>>>(batch, pw1, pb1, pw2, pb2, out);
}